// Round 2
// baseline (449.234 us; speedup 1.0000x reference)
//
#include <hip/hip_runtime.h>

typedef __attribute__((ext_vector_type(8))) short short8;
typedef __attribute__((ext_vector_type(4))) float float4f;

#define PADX 132
#define LOG_SLOPE -2.302585092994046f   // log(0.1)

__device__ __forceinline__ float bf2f(unsigned int u) {
    return __builtin_bit_cast(float, u << 16);
}
__device__ __forceinline__ unsigned short f2bf(float f) {
    unsigned int x = __builtin_bit_cast(unsigned int, f);
    x += 0x7fff + ((x >> 16) & 1);   // round-to-nearest-even
    return (unsigned short)(x >> 16);
}

template<int ISF32>
__device__ __forceinline__ float ldv(const void* p, int i) {
    if (ISF32) return ((const float*)p)[i];
    return bf2f(((const unsigned short*)p)[i]);
}

__device__ __forceinline__ float4f mfma16(short8 a, short8 b, float4f c) {
    return __builtin_amdgcn_mfma_f32_16x16x32_bf16(a, b, c, 0, 0, 0);
}

__device__ __forceinline__ void split8(float4f a, float4f b, short8& hi, short8& lo) {
#pragma unroll
    for (int j = 0; j < 4; ++j) {
        float v = a[j]; unsigned short h = f2bf(v);
        hi[j] = (short)h; lo[j] = (short)f2bf(v - bf2f(h));
        v = b[j]; h = f2bf(v);
        hi[4 + j] = (short)h; lo[4 + j] = (short)f2bf(v - bf2f(h));
    }
}

// out[16x128] = act( in[16x128] @ W^T + bias )
// MODE 0: out = leaky(v) | 1: out += v | 2: out = leaky(v) + count | 3: count only
template<int MODE, int ISF32>
__device__ __forceinline__ void matvec(const float* in, float* out,
                                       const void* __restrict__ W, int wofs,
                                       const void* __restrict__ bias, int bofs,
                                       int lane, int colb, int* cnt) {
    const int m = lane & 15, q = lane >> 4;
    const int c0 = colb + m, c1 = colb + 16 + m;
    float b0 = ldv<ISF32>(bias, bofs + c0);
    float b1v = ldv<ISF32>(bias, bofs + c1);
    float4f acc0 = {b0, b0, b0, b0};
    float4f acc1 = {b1v, b1v, b1v, b1v};
    __syncthreads();   // previous epilogue's writes to `in` now visible
#pragma unroll
    for (int kk = 0; kk < 4; ++kk) {
        const int kc = kk * 32 + q * 8;
        const float* xp = in + m * PADX + kc;
        short8 xh, xl;
        split8(*(const float4f*)xp, *(const float4f*)(xp + 4), xh, xl);
        if (ISF32) {
            const float* w0p = (const float*)W + wofs + c0 * 128 + kc;
            const float* w1p = (const float*)W + wofs + c1 * 128 + kc;
            short8 w0h, w0l, w1h, w1l;
            split8(*(const float4f*)w0p, *(const float4f*)(w0p + 4), w0h, w0l);
            split8(*(const float4f*)w1p, *(const float4f*)(w1p + 4), w1h, w1l);
            acc0 = mfma16(xh, w0h, acc0);
            acc0 = mfma16(xl, w0h, acc0);
            acc0 = mfma16(xh, w0l, acc0);
            acc1 = mfma16(xh, w1h, acc1);
            acc1 = mfma16(xl, w1h, acc1);
            acc1 = mfma16(xh, w1l, acc1);
        } else {
            short8 w0 = *(const short8*)((const unsigned short*)W + wofs + c0 * 128 + kc);
            short8 w1 = *(const short8*)((const unsigned short*)W + wofs + c1 * 128 + kc);
            acc0 = mfma16(xh, w0, acc0);
            acc0 = mfma16(xl, w0, acc0);
            acc1 = mfma16(xh, w1, acc1);
            acc1 = mfma16(xl, w1, acc1);
        }
    }
    __syncthreads();   // all reads of `in` done; in-place epilogue safe
    const int rbase = q * 4;
    int c[4];
#pragma unroll
    for (int r = 0; r < 4; ++r) {
        float v0 = acc0[r], v1 = acc1[r];
        int row = rbase + r;
        if (MODE == 1) {
            out[row * PADX + c0] += v0;
            out[row * PADX + c1] += v1;
        } else {
            if (MODE >= 2) c[r] = (v0 <= 0.0f) + (v1 <= 0.0f);
            if (MODE != 3) {
                out[row * PADX + c0] = v0 > 0.0f ? v0 : 0.1f * v0;
                out[row * PADX + c1] = v1 > 0.0f ? v1 : 0.1f * v1;
            }
        }
    }
    if (MODE >= 2) {
#pragma unroll
        for (int r = 0; r < 4; ++r) {
            int cc = c[r];
            cc += __shfl_xor(cc, 1);
            cc += __shfl_xor(cc, 2);
            cc += __shfl_xor(cc, 4);
            cc += __shfl_xor(cc, 8);
            if (m == 0) atomicAdd(&cnt[rbase + r], cc);
        }
    }
}

template<int ISF32>
__device__ __forceinline__ void fwd(int bid, int tid, int lane, float* lds,
        const void* x, const void* W1, const void* b1, const void* W2, const void* b2,
        const void* W3, const void* b3, void* out, float* ws) {
    const int r0 = bid * 16;
    float* X = lds;                      // [16][PADX]
    float* T = lds + 16 * PADX;          // [16][PADX]
    int* cnt = (int*)(lds + 32 * PADX);  // [16]
    for (int e = tid; e < 2048; e += 256) {
        int r = e >> 7, c = e & 127;
        X[r * PADX + c] = ldv<ISF32>(x, (r0 + r) * 128 + c);
    }
    if (tid < 16) cnt[tid] = 0;
    const int colb = (tid >> 6) * 32;
#pragma unroll 1
    for (int layer = 0; layer < 4; ++layer) {
        const int wofs = layer * 16384, bofs = layer * 128;
        matvec<0, ISF32>(X, T, W1, wofs, b1, bofs, lane, colb, cnt);  // T = leaky(h1)
        matvec<0, ISF32>(T, T, W2, wofs, b2, bofs, lane, colb, cnt);  // T = leaky(h2)
        matvec<1, ISF32>(T, X, W3, wofs, b3, bofs, lane, colb, cnt);  // X += f
        matvec<2, ISF32>(X, T, W1, wofs, b1, bofs, lane, colb, cnt);  // leaky(g1), count
        matvec<3, ISF32>(T, T, W2, wofs, b2, bofs, lane, colb, cnt);  // count g2
    }
    __syncthreads();
    for (int e = tid; e < 2048; e += 256) {
        int r = e >> 7, c = e & 127;
        float v = X[r * PADX + c];
        if (ISF32) ((float*)out)[(r0 + r) * 128 + c] = v;
        else ((unsigned short*)out)[(r0 + r) * 128 + c] = f2bf(v);
    }
    if (tid < 16) ws[64 + r0 + tid] = (float)cnt[tid];
}

__global__ void k_detect(const unsigned short* __restrict__ W1u, float* __restrict__ ws) {
    // If W1 is fp32, even-indexed u16s are raw mantissa bits (uniform);
    // if bf16, they are valid small bf16 values (exponent field ~[100,125]).
    int lane = threadIdx.x & 63;
    unsigned int u = W1u[lane * 2];
    unsigned int e = (u >> 7) & 0xFF;
    int bad = (e < 64) || (e > 135);
    unsigned long long msk = __ballot(bad);
    if (lane == 0) ws[1] = (msk != 0ull) ? 1.0f : 0.0f;
}

__global__ __launch_bounds__(256) void k_main(
        const void* __restrict__ x,
        const void* __restrict__ W1, const void* __restrict__ b1,
        const void* __restrict__ W2, const void* __restrict__ b2,
        const void* __restrict__ W3, const void* __restrict__ b3,
        void* __restrict__ out, float* __restrict__ ws) {
    __shared__ float lds[16384];   // 64 KB
    const int tid = threadIdx.x;
    const int lane = tid & 63;
    const int isf32 = (ws[1] != 0.0f);

    if (blockIdx.x < 12) {
        // ---------- log|det W| via LU with partial pivoting ----------
        const int id = blockIdx.x;
        const int wsel = id % 3, layer = id / 3;
        const void* Wm = (wsel == 0 ? W1 : (wsel == 1 ? W2 : W3));
        const int ofs = layer * 16384;
        float* A = lds;   // 128 x 128 fp32
        for (int e = tid; e < 16384; e += 256)
            A[e] = isf32 ? ((const float*)Wm)[ofs + e]
                         : bf2f(((const unsigned short*)Wm)[ofs + e]);
        __syncthreads();
        float logacc = 0.0f;
        for (int k = 0; k < 128; ++k) {
            float v = -1.0f; int idx = k;
            int i1 = k + lane;
            if (i1 < 128) { v = fabsf(A[i1 * 128 + k]); idx = i1; }
            int i2 = i1 + 64;
            if (i2 < 128) {
                float v2 = fabsf(A[i2 * 128 + k]);
                if (v2 > v) { v = v2; idx = i2; }
            }
#pragma unroll
            for (int off = 32; off; off >>= 1) {
                float ov = __shfl_xor(v, off);
                int   oi = __shfl_xor(idx, off);
                if (ov > v || (ov == v && oi < idx)) { v = ov; idx = oi; }
            }
            float pv = A[idx * 128 + k];
            logacc += logf(fabsf(pv));
            float rp = 1.0f / pv;
            __syncthreads();
            if (idx != k && tid < 128 - k) {
                int j = k + tid;
                float a = A[k * 128 + j], b = A[idx * 128 + j];
                A[k * 128 + j] = b; A[idx * 128 + j] = a;
            }
            __syncthreads();
            const int ty = tid >> 5, tx = tid & 31;
            for (int i = k + 1 + ty; i < 128; i += 8) {
                float f = A[i * 128 + k] * rp;
                for (int j = k + 1 + tx; j < 128; j += 32)
                    A[i * 128 + j] -= f * A[k * 128 + j];
            }
            __syncthreads();
        }
        if (tid == 0) atomicAdd(&ws[0], logacc);
        return;
    }

    const int bid = blockIdx.x - 12;
    if (isf32) fwd<1>(bid, tid, lane, lds, x, W1, b1, W2, b2, W3, b3, out, ws);
    else       fwd<0>(bid, tid, lane, lds, x, W1, b1, W2, b2, W3, b3, out, ws);
}

__global__ void k_fin(const float* __restrict__ ws, void* __restrict__ out) {
    int b = blockIdx.x * 256 + threadIdx.x;
    if (b < 4096) {
        float v = ws[0] + LOG_SLOPE * ws[64 + b];
        if (ws[1] != 0.0f) ((float*)out)[524288 + b] = v;
        else ((unsigned short*)out)[524288 + b] = f2bf(v);
    }
}

extern "C" void kernel_launch(void* const* d_in, const int* in_sizes, int n_in,
                              void* d_out, int out_size, void* d_ws, size_t ws_size,
                              hipStream_t stream) {
    const void* x  = d_in[0];
    const void* W1 = d_in[1];
    const void* b1 = d_in[2];
    const void* W2 = d_in[3];
    const void* b2 = d_in[4];
    const void* W3 = d_in[5];
    const void* b3 = d_in[6];
    float* ws = (float*)d_ws;

    hipMemsetAsync(d_ws, 0, 8, stream);  // zero ws[0] (logdetW accumulator)
    hipLaunchKernelGGL(k_detect, dim3(1), dim3(64), 0, stream,
                       (const unsigned short*)W1, ws);
    hipLaunchKernelGGL(k_main, dim3(268), dim3(256), 0, stream,
                       x, W1, b1, W2, b2, W3, b3, d_out, ws);
    hipLaunchKernelGGL(k_fin, dim3(16), dim3(256), 0, stream, ws, d_out);
}